// Round 18
// baseline (216.964 us; speedup 1.0000x reference)
//
#include <hip/hip_runtime.h>
#include <stdint.h>

#define NSEQ   4096
#define BATCH  2
#define NHEAD  8
#define DHEAD  64
#define DIM    512
#define NQKV   1536
#define MROWS  (BATCH*NSEQ)   // 8192
#define NBH    (BATCH*NHEAD)  // 16

typedef float  f32x4 __attribute__((ext_vector_type(4)));
typedef short  s16x8 __attribute__((ext_vector_type(8)));

__device__ __forceinline__ unsigned short f2b(float f){
  unsigned int u = __float_as_uint(f);
  u += 0x7FFFu + ((u >> 16) & 1u);
  return (unsigned short)(u >> 16);
}
__device__ __forceinline__ float b2f(unsigned short h){
  return __uint_as_float(((unsigned int)h) << 16);
}
__device__ __forceinline__ void gld_lds16(const void* g, void* l){
  __builtin_amdgcn_global_load_lds((const __attribute__((address_space(1))) unsigned int*)g,
                                   (__attribute__((address_space(3))) unsigned int*)l, 16, 0, 0);
}
// Schraudolph fast exp2 on the VALU pipe (v_fma + v_cvt_i32). Rel err <= ~4%.
__device__ __forceinline__ float fexp2(float x){
  return __uint_as_float((unsigned)(int)__builtin_fmaf(x, 8388608.f, 1064866805.f));
}

// ---------------- fused prep: x->bf16, wqkv^T->bf16, wout^T->bf16 ----------------
__global__ void k_prep(const float* __restrict__ x, unsigned short* __restrict__ xb,
                       const float* __restrict__ wqkv, unsigned short* __restrict__ wqT,
                       const float* __restrict__ wout, unsigned short* __restrict__ woT){
  __shared__ float t[32][33];
  const int b = blockIdx.x;
  if (b < 4096){                       // cvt: 8192x512 via float4
    const int i = b*256 + threadIdx.x;
    float4 v = ((const float4*)x)[i];
    ushort4 o;
    o.x = f2b(v.x); o.y = f2b(v.y); o.z = f2b(v.z); o.w = f2b(v.w);
    ((ushort4*)xb)[i] = o;
  } else {
    const float* in; unsigned short* out; int R, C, cb, rb;
    if (b < 4096 + 768){               // wqkv [512][1536] -> [1536][512]
      const int q = b - 4096; in = wqkv; out = wqT; R = DIM; C = NQKV;
      cb = (q % 48)*32; rb = (q / 48)*32;
    } else {                           // wout [512][512] -> [512][512]
      const int q = b - 4096 - 768; in = wout; out = woT; R = DIM; C = DIM;
      cb = (q & 15)*32; rb = (q >> 4)*32;
    }
    const int tx = threadIdx.x & 31, ty = threadIdx.x >> 5;
    #pragma unroll
    for (int s = 0; s < 32; s += 8) t[ty+s][tx] = in[(size_t)(rb+ty+s)*C + cb + tx];
    __syncthreads();
    #pragma unroll
    for (int s = 0; s < 32; s += 8) out[(size_t)(cb+ty+s)*R + rb + tx] = f2b(t[tx][ty+s]);
  }
}

// ---------------- QKV GEMM: [8192][512] @ [512][1536] (B given transposed) ----------------
#define QSTAGE(KS, B) do{ \
    const int k0_ = (KS)*32; \
    _Pragma("unroll") \
    for (int i_ = 0; i_ < 2; ++i_){ \
      const int slot_ = w*2 + i_; \
      const int r_ = slot_*16 + (lane>>2); \
      const int ch_ = (lane&3) ^ (r_&3); \
      gld_lds16(A  + (size_t)(m0+r_)*DIM + k0_ + ch_*8, (char*)at[B] + slot_*1024); \
      gld_lds16(Bt + (size_t)(n0+r_)*DIM + k0_ + ch_*8, (char*)bt[B] + slot_*1024); \
    }}while(0)

__global__ __launch_bounds__(256) void k_qkv_gemm(
    const unsigned short* __restrict__ A,   // xb  [8192][512]
    const unsigned short* __restrict__ Bt,  // wqT [1536][512]
    unsigned short* __restrict__ qbuf, unsigned short* __restrict__ kbuf,
    unsigned short* __restrict__ vbuf){
  __shared__ __align__(16) unsigned short at[2][128*32];
  __shared__ __align__(16) unsigned short bt[2][128*32];
  const int n0 = blockIdx.x*128, m0 = blockIdx.y*128;
  const int tid = threadIdx.x, w = tid>>6, lane = tid&63;
  const int wr = (w>>1)*64, wc = (w&1)*64;
  f32x4 acc[4][4] = {};
  QSTAGE(0, 0);
  for (int ks = 0; ks < 16; ++ks){
    __syncthreads();
    if (ks < 15) QSTAGE(ks+1, (ks+1)&1);
    const unsigned short* atc = at[ks&1];
    const unsigned short* btc = bt[ks&1];
    s16x8 af[4], bfr[4];
    #pragma unroll
    for (int f = 0; f < 4; ++f){
      const int rr = wr + f*16 + (lane&15);
      af[f]  = *(const s16x8*)((const char*)atc + rr*64 + ((((lane>>4)) ^ (rr&3))<<4));
      const int cc = wc + f*16 + (lane&15);
      bfr[f] = *(const s16x8*)((const char*)btc + cc*64 + ((((lane>>4)) ^ (cc&3))<<4));
    }
    #pragma unroll
    for (int fr = 0; fr < 4; ++fr)
      #pragma unroll
      for (int fc = 0; fc < 4; ++fc)
        acc[fr][fc] = __builtin_amdgcn_mfma_f32_16x16x32_bf16(bfr[fc], af[fr], acc[fr][fc], 0,0,0);
  }
  const float QS = 0.18033688011112042f;
  #pragma unroll
  for (int fr = 0; fr < 4; ++fr){
    const int row = m0 + wr + fr*16 + (lane&15);
    const int b = row >> 12, n = row & 4095;
    #pragma unroll
    for (int fc = 0; fc < 4; ++fc){
      const int col0 = n0 + wc + fc*16 + ((lane>>4)<<2);
      const int which = col0 >> 9;
      const int h = (col0 & 511) >> 6;
      const int d = col0 & 63;
      unsigned short* dst = (which==0) ? qbuf : ((which==1) ? kbuf : vbuf);
      const float sc = (which==0) ? QS : 1.f;
      ushort4 o;
      o.x = f2b(acc[fr][fc][0]*sc);
      o.y = f2b(acc[fr][fc][1]*sc);
      o.z = f2b(acc[fr][fc][2]*sc);
      o.w = f2b(acc[fr][fc][3]*sc);
      *(ushort4*)(dst + (size_t)((b*NHEAD + h)*NSEQ + n)*DHEAD + d) = o;
    }
  }
}

// ---------------- T = K^T V partials: 16 j-chunks, f32 coalesced stores ----------------
__global__ __launch_bounds__(256) void k_tpart(
    const unsigned short* __restrict__ kbuf, const unsigned short* __restrict__ vbuf,
    float* __restrict__ tpartf, float* __restrict__ vsp){
  __shared__ __align__(16) unsigned short kt[64*64];
  __shared__ __align__(16) unsigned short vt[64*64];
  const int bh = blockIdx.y, jc = blockIdx.x;   // jc: 0..15
  const unsigned short* K = kbuf + (size_t)bh*NSEQ*DHEAD;
  const unsigned short* V = vbuf + (size_t)bh*NSEQ*DHEAD;
  const int tid = threadIdx.x;
  const int d1 = (tid>>4)<<2, d2 = (tid&15)<<2;
  float accT[4][4] = {{0.f}};
  float accV[4] = {0.f,0.f,0.f,0.f};
  for (int st = 0; st < 4; ++st){
    const int j0 = jc*256 + st*64;
    __syncthreads();
    #pragma unroll
    for (int c = 0; c < 2; ++c){
      const int q = tid + 256*c;
      const int row = q>>3, ch = q&7;
      *(float4*)((char*)kt + row*128 + ch*16) = *(const float4*)((const char*)K + (size_t)(j0+row)*128 + ch*16);
      *(float4*)((char*)vt + row*128 + ch*16) = *(const float4*)((const char*)V + (size_t)(j0+row)*128 + ch*16);
    }
    __syncthreads();
    for (int jj = 0; jj < 64; ++jj){
      const ushort4 k4 = *(const ushort4*)(kt + jj*64 + d1);
      const ushort4 v4 = *(const ushort4*)(vt + jj*64 + d2);
      float kf[4] = {b2f(k4.x), b2f(k4.y), b2f(k4.z), b2f(k4.w)};
      float vf[4] = {b2f(v4.x), b2f(v4.y), b2f(v4.z), b2f(v4.w)};
      #pragma unroll
      for (int a = 0; a < 4; ++a)
        #pragma unroll
        for (int b = 0; b < 4; ++b) accT[a][b] += kf[a]*vf[b];
      #pragma unroll
      for (int b = 0; b < 4; ++b) accV[b] += vf[b];
    }
  }
  float* tp = tpartf + ((size_t)bh*16 + jc)*4096;
  #pragma unroll
  for (int a = 0; a < 4; ++a){
    float4 o; o.x = accT[a][0]; o.y = accT[a][1]; o.z = accT[a][2]; o.w = accT[a][3];
    *(float4*)&tp[(d1+a)*64 + d2] = o;
  }
  if (tid < 16){
    #pragma unroll
    for (int b = 0; b < 4; ++b) vsp[((size_t)bh*16 + jc)*64 + d2 + b] = accV[b];
  }
}

// reduce 16 f32 partials; store T transposed; zero the attn group counters
__global__ void k_tred(const float* __restrict__ tpartf, const float* __restrict__ vsp,
                       unsigned short* __restrict__ TB, float* __restrict__ vsum,
                       int* __restrict__ done){
  const int blk = blockIdx.x;            // 0..255
  const int bh = blk >> 4, part = blk & 15;
  const int tid = threadIdx.x;
  if (tid == 0) done[blk] = 0;           // one counter per (bh,qchunk) group
  const int idx = part*256 + tid;
  const int dd1 = idx>>6, dd2 = idx&63;
  float s = 0.f;
  #pragma unroll
  for (int pr = 0; pr < 16; ++pr) s += tpartf[((size_t)bh*16 + pr)*4096 + idx];
  TB[(size_t)bh*4096 + dd2*64 + dd1] = f2b(s);
  if (part == 0 && tid < 64){
    float v = 0.f;
    #pragma unroll
    for (int pr = 0; pr < 16; ++pr) v += vsp[((size_t)bh*16 + pr)*64 + tid];
    vsum[bh*64 + tid] = v;
  }
}

// ---------------- LSE scan + fused finish (last block of each (bh,qchunk) group) ----------
// 1024 blocks = 8 xcd x 2 bh x 16 qchunk x 4 jq; 4 waves x 64 q-rows.
// After ps write, threadfence+atomic; the 4th arriver of each group runs the
// fin epilogue (O = ln2*(Q'@T - lse2*Vsum)) reusing its in-register Q frags.
// Output identical regardless of winner (same q0 -> same aq) => deterministic.
#define ASTAGE(U, BUFI) do { \
    const int ti_ = jbase + (((U)+phase)&15); \
    const size_t o_ = (size_t)ti_*64*DHEAD; \
    char* d_ = (char*)kt[BUFI]; \
    gld_lds16(kg0 + o_, d_ + s0*1024); \
    gld_lds16(kg1 + o_, d_ + s1*1024); } while(0)

#define ATILE(BUFI) do { \
    const char* buf_ = (const char*)kt[BUFI]; \
    _Pragma("unroll") \
    for (int kk = 0; kk < 4; ++kk){ \
      const int r_ = kk*16 + (lane&15); \
      const s16x8 b0_ = *(const s16x8*)(buf_ + r_*128 + ((((lane>>4))   ^ (r_&7))<<4)); \
      const s16x8 b1_ = *(const s16x8*)(buf_ + r_*128 + (((4+(lane>>4)) ^ (r_&7))<<4)); \
      f32x4 a0_ = {0.f,0.f,0.f,0.f}, a1_ = {0.f,0.f,0.f,0.f}; \
      f32x4 a2_ = {0.f,0.f,0.f,0.f}, a3_ = {0.f,0.f,0.f,0.f}; \
      __builtin_amdgcn_s_setprio(1); \
      a0_ = __builtin_amdgcn_mfma_f32_16x16x32_bf16(aq[0][0], b0_, a0_, 0,0,0); \
      a0_ = __builtin_amdgcn_mfma_f32_16x16x32_bf16(aq[0][1], b1_, a0_, 0,0,0); \
      a1_ = __builtin_amdgcn_mfma_f32_16x16x32_bf16(aq[1][0], b0_, a1_, 0,0,0); \
      a1_ = __builtin_amdgcn_mfma_f32_16x16x32_bf16(aq[1][1], b1_, a1_, 0,0,0); \
      a2_ = __builtin_amdgcn_mfma_f32_16x16x32_bf16(aq[2][0], b0_, a2_, 0,0,0); \
      a2_ = __builtin_amdgcn_mfma_f32_16x16x32_bf16(aq[2][1], b1_, a2_, 0,0,0); \
      a3_ = __builtin_amdgcn_mfma_f32_16x16x32_bf16(aq[3][0], b0_, a3_, 0,0,0); \
      a3_ = __builtin_amdgcn_mfma_f32_16x16x32_bf16(aq[3][1], b1_, a3_, 0,0,0); \
      __builtin_amdgcn_s_setprio(0); \
      _Pragma("unroll") \
      for (int rr = 0; rr < 4; ++rr){ \
        lsum[0][rr] += __builtin_amdgcn_exp2f(a0_[rr]); \
        lsum[1][rr] += __builtin_amdgcn_exp2f(a1_[rr]); \
        lsum[2][rr] += __builtin_amdgcn_exp2f(a2_[rr]); \
        lsum[3][rr] += fexp2(a3_[rr]); \
      } \
    } } while(0)

#define APHASE(U) do { \
    if ((U) <= 13)      { asm volatile("s_waitcnt vmcnt(4)" ::: "memory"); } \
    else if ((U) == 14) { asm volatile("s_waitcnt vmcnt(2)" ::: "memory"); } \
    else                { asm volatile("s_waitcnt vmcnt(0)" ::: "memory"); } \
    __builtin_amdgcn_s_barrier(); \
    asm volatile("" ::: "memory"); \
    if ((U) <= 12) ASTAGE((U)+3, ((U)+3)&3); \
    ATILE((U)&3); } while(0)

__global__ __launch_bounds__(256) void k_attn(
    const unsigned short* __restrict__ qbuf, const unsigned short* __restrict__ kbuf,
    const unsigned short* __restrict__ TB, const float* __restrict__ vsum,
    float* __restrict__ ps, int* __restrict__ done,
    unsigned short* __restrict__ om){
  __shared__ __align__(16) unsigned short kt[4][64*64]; // 4 x 8KB
  __shared__ int lastflag;
  const int bid = blockIdx.x;
  const int idx = bid >> 3;                  // 0..127
  const int bh  = ((bid & 7) << 1) + (idx >> 6);
  const int rest = idx & 63;
  const int qchunk = rest >> 2;              // 0..15 (256 q-rows each)
  const int js = rest & 3;                   // j quarter: 16 tiles
  const int tid = threadIdx.x, w = tid>>6, lane = tid&63;
  const int q0 = qchunk*256 + w*64;          // this wave's 64 q-rows
  const unsigned short* Q = qbuf + (size_t)bh*NSEQ*DHEAD;
  const unsigned short* K = kbuf + (size_t)bh*NSEQ*DHEAD;

  s16x8 aq[4][2];
  #pragma unroll
  for (int g = 0; g < 4; ++g){
    const int qrow = q0 + g*16 + (lane&15);
    aq[g][0] = *(const s16x8*)(Q + (size_t)qrow*DHEAD + ((lane>>4)<<3));
    aq[g][1] = *(const s16x8*)(Q + (size_t)qrow*DHEAD + 32 + ((lane>>4)<<3));
  }

  const int s0 = w*2, s1 = w*2 + 1;
  const int srow0 = s0*8 + (lane>>3), srow1 = s1*8 + (lane>>3);
  const int sch = ((lane&7) ^ (lane>>3));
  const unsigned short* kg0 = K + (size_t)srow0*DHEAD + sch*8;
  const unsigned short* kg1 = K + (size_t)srow1*DHEAD + sch*8;

  const int phase = (idx*5) & 15;
  const int jbase = js*16;

  ASTAGE(0, 0);
  ASTAGE(1, 1);
  ASTAGE(2, 2);

  float lsum[4][4] = {};
  APHASE(0);  APHASE(1);  APHASE(2);  APHASE(3);
  APHASE(4);  APHASE(5);  APHASE(6);  APHASE(7);
  APHASE(8);  APHASE(9);  APHASE(10); APHASE(11);
  APHASE(12); APHASE(13); APHASE(14); APHASE(15);

  #pragma unroll
  for (int m = 1; m < 16; m <<= 1)
    #pragma unroll
    for (int g = 0; g < 4; ++g)
      #pragma unroll
      for (int r = 0; r < 4; ++r) lsum[g][r] += __shfl_xor(lsum[g][r], m, 16);

  if ((lane&15) == 0){
    float* pp = ps + ((size_t)js*NBH + bh)*NSEQ;
    #pragma unroll
    for (int g = 0; g < 4; ++g)
      #pragma unroll
      for (int r = 0; r < 4; ++r)
        pp[q0 + g*16 + (lane>>4)*4 + r] = lsum[g][r];
  }

  // ---- group handoff: 4th arriver of (bh,qchunk) runs the finish ----
  __threadfence();
  if (tid == 0) lastflag = atomicAdd(&done[bh*16 + qchunk], 1);
  __syncthreads();
  if (lastflag != 3) return;
  __threadfence();

  const float* p0 = ps + (size_t)bh*NSEQ;
  const float* p1 = ps + ((size_t)NBH   + bh)*NSEQ;
  const float* p2 = ps + ((size_t)2*NBH + bh)*NSEQ;
  const float* p3 = ps + ((size_t)3*NBH + bh)*NSEQ;
  float lse2[4][4];
  #pragma unroll
  for (int g = 0; g < 4; ++g)
    #pragma unroll
    for (int r = 0; r < 4; ++r){
      const int n = q0 + g*16 + (lane>>4)*4 + r;
      lse2[g][r] = log2f((p0[n] + p1[n]) + (p2[n] + p3[n]));
    }
  const unsigned short* tb = TB + (size_t)bh*4096;
  const int b = bh>>3, h = bh&7;
  #pragma unroll
  for (int fc = 0; fc < 4; ++fc){
    const int d2 = fc*16 + (lane&15);
    const s16x8 t0 = *(const s16x8*)(tb + d2*64 + ((lane>>4)<<3));
    const s16x8 t1 = *(const s16x8*)(tb + d2*64 + 32 + ((lane>>4)<<3));
    const float vs = vsum[bh*64 + d2];
    #pragma unroll
    for (int g = 0; g < 4; ++g){
      f32x4 acc = {0.f,0.f,0.f,0.f};
      acc = __builtin_amdgcn_mfma_f32_16x16x32_bf16(aq[g][0], t0, acc, 0,0,0);
      acc = __builtin_amdgcn_mfma_f32_16x16x32_bf16(aq[g][1], t1, acc, 0,0,0);
      #pragma unroll
      for (int r = 0; r < 4; ++r){
        const int n = q0 + g*16 + (lane>>4)*4 + r;
        const float val = 0.6931471805599453f * (acc[r] - lse2[g][r]*vs);
        om[((size_t)b*NSEQ + n)*DIM + h*DHEAD + d2] = f2b(val);
      }
    }
  }
}

// ---------------- out GEMM: om[8192][512] @ w_out[512][512] + bias + residual ----------------
#define OSTAGE(KS, B) do{ \
    const int k0_ = (KS)*32; \
    _Pragma("unroll") \
    for (int i_ = 0; i_ < 2; ++i_){ \
      const int slot_ = w*2 + i_; \
      const int r_ = slot_*16 + (lane>>2); \
      const int ch_ = (lane&3) ^ (r_&3); \
      gld_lds16(A  + (size_t)(m0+r_)*DIM + k0_ + ch_*8, (char*)at[B] + slot_*1024); \
      gld_lds16(Bt + (size_t)(n0+r_)*DIM + k0_ + ch_*8, (char*)bt[B] + slot_*1024); \
    }}while(0)

__global__ __launch_bounds__(256) void k_out_gemm(
    const unsigned short* __restrict__ A,   // om  [8192][512]
    const unsigned short* __restrict__ Bt,  // woT [512][512]
    const float* __restrict__ bias, const float* __restrict__ xres,
    float* __restrict__ out){
  __shared__ __align__(16) unsigned short at[2][128*32];
  __shared__ __align__(16) unsigned short bt[2][128*32];
  const int n0 = blockIdx.x*128, m0 = blockIdx.y*128;
  const int tid = threadIdx.x, w = tid>>6, lane = tid&63;
  const int wr = (w>>1)*64, wc = (w&1)*64;
  f32x4 acc[4][4] = {};
  OSTAGE(0, 0);
  for (int ks = 0; ks < 16; ++ks){
    __syncthreads();
    if (ks < 15) OSTAGE(ks+1, (ks+1)&1);
    const unsigned short* atc = at[ks&1];
    const unsigned short* btc = bt[ks&1];
    s16x8 af[4], bfr[4];
    #pragma unroll
    for (int f = 0; f < 4; ++f){
      const int rr = wr + f*16 + (lane&15);
      af[f]  = *(const s16x8*)((const char*)atc + rr*64 + ((((lane>>4)) ^ (rr&3))<<4));
      const int cc = wc + f*16 + (lane&15);
      bfr[f] = *(const s16x8*)((const char*)btc + cc*64 + ((((lane>>4)) ^ (cc&3))<<4));
    }
    #pragma unroll
    for (int fr = 0; fr < 4; ++fr)
      #pragma unroll
      for (int fc = 0; fc < 4; ++fc)
        acc[fr][fc] = __builtin_amdgcn_mfma_f32_16x16x32_bf16(bfr[fc], af[fr], acc[fr][fc], 0,0,0);
  }
  #pragma unroll
  for (int fr = 0; fr < 4; ++fr){
    const int row = m0 + wr + fr*16 + (lane&15);
    #pragma unroll
    for (int fc = 0; fc < 4; ++fc){
      const int col0 = n0 + wc + fc*16 + ((lane>>4)<<2);
      const float4 bb = *(const float4*)&bias[col0];
      const float4 xr = *(const float4*)&xres[(size_t)row*DIM + col0];
      float4 o;
      o.x = acc[fr][fc][0] + bb.x + xr.x;
      o.y = acc[fr][fc][1] + bb.y + xr.y;
      o.z = acc[fr][fc][2] + bb.z + xr.z;
      o.w = acc[fr][fc][3] + bb.w + xr.w;
      *(float4*)&out[(size_t)row*DIM + col0] = o;
    }
  }
}

extern "C" void kernel_launch(void* const* d_in, const int* in_sizes, int n_in,
                              void* d_out, int out_size, void* d_ws, size_t ws_size,
                              hipStream_t stream){
  const float* x    = (const float*)d_in[0];
  const float* wqkv = (const float*)d_in[1];
  const float* wout = (const float*)d_in[2];
  const float* bout = (const float*)d_in[3];
  float* out = (float*)d_out;

  char* p = (char*)d_ws;
  unsigned short* xb   = (unsigned short*)p; p += (size_t)MROWS*DIM*2;
  unsigned short* wqT  = (unsigned short*)p; p += (size_t)NQKV*DIM*2;
  unsigned short* woT  = (unsigned short*)p; p += (size_t)DIM*DIM*2;
  unsigned short* qbuf = (unsigned short*)p; p += (size_t)NBH*NSEQ*DHEAD*2;
  unsigned short* kbuf = (unsigned short*)p; p += (size_t)NBH*NSEQ*DHEAD*2;
  unsigned short* vbuf = (unsigned short*)p; p += (size_t)NBH*NSEQ*DHEAD*2;
  float* tpartf        = (float*)p;          p += (size_t)NBH*16*4096*4;
  float* vsp           = (float*)p;          p += (size_t)NBH*16*64*4;
  unsigned short* TB   = (unsigned short*)p; p += (size_t)NBH*64*64*2;
  float* vsum          = (float*)p;          p += (size_t)NBH*64*4;
  unsigned short* om   = (unsigned short*)p; p += (size_t)MROWS*DIM*2;
  float* ps            = (float*)p;          p += (size_t)4*NBH*NSEQ*4;
  int* done            = (int*)p;            p += 256*4;

  k_prep<<<dim3(4096 + 768 + 256), dim3(256), 0, stream>>>(x, xb, wqkv, wqT, wout, woT);
  k_qkv_gemm<<<dim3(NQKV/128, MROWS/128), dim3(256), 0, stream>>>(xb, wqT, qbuf, kbuf, vbuf);
  k_tpart<<<dim3(16, NBH), dim3(256), 0, stream>>>(kbuf, vbuf, tpartf, vsp);
  k_tred<<<dim3(256), dim3(256), 0, stream>>>(tpartf, vsp, TB, vsum, done);
  k_attn<<<dim3(1024), dim3(256), 0, stream>>>(qbuf, kbuf, TB, vsum, ps, done, om);
  k_out_gemm<<<dim3(DIM/128, MROWS/128), dim3(256), 0, stream>>>(om, woT, bout, x, out);
}

// Round 19
// 119.705 us; speedup vs baseline: 1.8125x; 1.8125x over previous
//
#include <hip/hip_runtime.h>
#include <stdint.h>

#define NSEQ   4096
#define BATCH  2
#define NHEAD  8
#define DHEAD  64
#define DIM    512
#define NQKV   1536
#define MROWS  (BATCH*NSEQ)   // 8192
#define NBH    (BATCH*NHEAD)  // 16

typedef float  f32x4 __attribute__((ext_vector_type(4)));
typedef short  s16x8 __attribute__((ext_vector_type(8)));

__device__ __forceinline__ unsigned short f2b(float f){
  unsigned int u = __float_as_uint(f);
  u += 0x7FFFu + ((u >> 16) & 1u);
  return (unsigned short)(u >> 16);
}
__device__ __forceinline__ float b2f(unsigned short h){
  return __uint_as_float(((unsigned int)h) << 16);
}
__device__ __forceinline__ void gld_lds16(const void* g, void* l){
  __builtin_amdgcn_global_load_lds((const __attribute__((address_space(1))) unsigned int*)g,
                                   (__attribute__((address_space(3))) unsigned int*)l, 16, 0, 0);
}
// Schraudolph fast exp2 on the VALU pipe (v_fma + v_cvt_i32). Rel err <= ~4%.
__device__ __forceinline__ float fexp2(float x){
  return __uint_as_float((unsigned)(int)__builtin_fmaf(x, 8388608.f, 1064866805.f));
}

// ---------------- fused prep: x->bf16, wqkv^T->bf16, wout^T->bf16 ----------------
__global__ void k_prep(const float* __restrict__ x, unsigned short* __restrict__ xb,
                       const float* __restrict__ wqkv, unsigned short* __restrict__ wqT,
                       const float* __restrict__ wout, unsigned short* __restrict__ woT){
  __shared__ float t[32][33];
  const int b = blockIdx.x;
  if (b < 4096){                       // cvt: 8192x512 via float4
    const int i = b*256 + threadIdx.x;
    float4 v = ((const float4*)x)[i];
    ushort4 o;
    o.x = f2b(v.x); o.y = f2b(v.y); o.z = f2b(v.z); o.w = f2b(v.w);
    ((ushort4*)xb)[i] = o;
  } else {
    const float* in; unsigned short* out; int R, C, cb, rb;
    if (b < 4096 + 768){               // wqkv [512][1536] -> [1536][512]
      const int q = b - 4096; in = wqkv; out = wqT; R = DIM; C = NQKV;
      cb = (q % 48)*32; rb = (q / 48)*32;
    } else {                           // wout [512][512] -> [512][512]
      const int q = b - 4096 - 768; in = wout; out = woT; R = DIM; C = DIM;
      cb = (q & 15)*32; rb = (q >> 4)*32;
    }
    const int tx = threadIdx.x & 31, ty = threadIdx.x >> 5;
    #pragma unroll
    for (int s = 0; s < 32; s += 8) t[ty+s][tx] = in[(size_t)(rb+ty+s)*C + cb + tx];
    __syncthreads();
    #pragma unroll
    for (int s = 0; s < 32; s += 8) out[(size_t)(cb+ty+s)*R + rb + tx] = f2b(t[tx][ty+s]);
  }
}

// ---------------- QKV GEMM: [8192][512] @ [512][1536] (B given transposed) ----------------
// XCD-swizzled 1D grid (768 = 8 xcd x 96): each XCD owns 8 consecutive
// m-panels (A ~1MB) + full B (1.5MB) -> both L2-resident, no cross-die refetch.
#define QSTAGE(KS, B) do{ \
    const int k0_ = (KS)*32; \
    _Pragma("unroll") \
    for (int i_ = 0; i_ < 2; ++i_){ \
      const int slot_ = w*2 + i_; \
      const int r_ = slot_*16 + (lane>>2); \
      const int ch_ = (lane&3) ^ (r_&3); \
      gld_lds16(A  + (size_t)(m0+r_)*DIM + k0_ + ch_*8, (char*)at[B] + slot_*1024); \
      gld_lds16(Bt + (size_t)(n0+r_)*DIM + k0_ + ch_*8, (char*)bt[B] + slot_*1024); \
    }}while(0)

__global__ __launch_bounds__(256) void k_qkv_gemm(
    const unsigned short* __restrict__ A,   // xb  [8192][512]
    const unsigned short* __restrict__ Bt,  // wqT [1536][512]
    unsigned short* __restrict__ qbuf, unsigned short* __restrict__ kbuf,
    unsigned short* __restrict__ vbuf){
  __shared__ __align__(16) unsigned short at[2][128*32];
  __shared__ __align__(16) unsigned short bt[2][128*32];
  const int bid = blockIdx.x;
  const int swz = (bid & 7)*96 + (bid >> 3);   // bijective: 768 % 8 == 0
  const int n0 = (swz % 12)*128, m0 = (swz / 12)*128;
  const int tid = threadIdx.x, w = tid>>6, lane = tid&63;
  const int wr = (w>>1)*64, wc = (w&1)*64;
  f32x4 acc[4][4] = {};
  QSTAGE(0, 0);
  for (int ks = 0; ks < 16; ++ks){
    __syncthreads();
    if (ks < 15) QSTAGE(ks+1, (ks+1)&1);
    const unsigned short* atc = at[ks&1];
    const unsigned short* btc = bt[ks&1];
    s16x8 af[4], bfr[4];
    #pragma unroll
    for (int f = 0; f < 4; ++f){
      const int rr = wr + f*16 + (lane&15);
      af[f]  = *(const s16x8*)((const char*)atc + rr*64 + ((((lane>>4)) ^ (rr&3))<<4));
      const int cc = wc + f*16 + (lane&15);
      bfr[f] = *(const s16x8*)((const char*)btc + cc*64 + ((((lane>>4)) ^ (cc&3))<<4));
    }
    #pragma unroll
    for (int fr = 0; fr < 4; ++fr)
      #pragma unroll
      for (int fc = 0; fc < 4; ++fc)
        acc[fr][fc] = __builtin_amdgcn_mfma_f32_16x16x32_bf16(bfr[fc], af[fr], acc[fr][fc], 0,0,0);
  }
  const float QS = 0.18033688011112042f;
  #pragma unroll
  for (int fr = 0; fr < 4; ++fr){
    const int row = m0 + wr + fr*16 + (lane&15);
    const int b = row >> 12, n = row & 4095;
    #pragma unroll
    for (int fc = 0; fc < 4; ++fc){
      const int col0 = n0 + wc + fc*16 + ((lane>>4)<<2);
      const int which = col0 >> 9;
      const int h = (col0 & 511) >> 6;
      const int d = col0 & 63;
      unsigned short* dst = (which==0) ? qbuf : ((which==1) ? kbuf : vbuf);
      const float sc = (which==0) ? QS : 1.f;
      ushort4 o;
      o.x = f2b(acc[fr][fc][0]*sc);
      o.y = f2b(acc[fr][fc][1]*sc);
      o.z = f2b(acc[fr][fc][2]*sc);
      o.w = f2b(acc[fr][fc][3]*sc);
      *(ushort4*)(dst + (size_t)((b*NHEAD + h)*NSEQ + n)*DHEAD + d) = o;
    }
  }
}

// ---------------- T = K^T V partials: 16 j-chunks, f32 coalesced stores ----------------
__global__ __launch_bounds__(256) void k_tpart(
    const unsigned short* __restrict__ kbuf, const unsigned short* __restrict__ vbuf,
    float* __restrict__ tpartf, float* __restrict__ vsp){
  __shared__ __align__(16) unsigned short kt[64*64];
  __shared__ __align__(16) unsigned short vt[64*64];
  const int bh = blockIdx.y, jc = blockIdx.x;   // jc: 0..15
  const unsigned short* K = kbuf + (size_t)bh*NSEQ*DHEAD;
  const unsigned short* V = vbuf + (size_t)bh*NSEQ*DHEAD;
  const int tid = threadIdx.x;
  const int d1 = (tid>>4)<<2, d2 = (tid&15)<<2;
  float accT[4][4] = {{0.f}};
  float accV[4] = {0.f,0.f,0.f,0.f};
  for (int st = 0; st < 4; ++st){
    const int j0 = jc*256 + st*64;
    __syncthreads();
    #pragma unroll
    for (int c = 0; c < 2; ++c){
      const int q = tid + 256*c;
      const int row = q>>3, ch = q&7;
      *(float4*)((char*)kt + row*128 + ch*16) = *(const float4*)((const char*)K + (size_t)(j0+row)*128 + ch*16);
      *(float4*)((char*)vt + row*128 + ch*16) = *(const float4*)((const char*)V + (size_t)(j0+row)*128 + ch*16);
    }
    __syncthreads();
    for (int jj = 0; jj < 64; ++jj){
      const ushort4 k4 = *(const ushort4*)(kt + jj*64 + d1);
      const ushort4 v4 = *(const ushort4*)(vt + jj*64 + d2);
      float kf[4] = {b2f(k4.x), b2f(k4.y), b2f(k4.z), b2f(k4.w)};
      float vf[4] = {b2f(v4.x), b2f(v4.y), b2f(v4.z), b2f(v4.w)};
      #pragma unroll
      for (int a = 0; a < 4; ++a)
        #pragma unroll
        for (int b = 0; b < 4; ++b) accT[a][b] += kf[a]*vf[b];
      #pragma unroll
      for (int b = 0; b < 4; ++b) accV[b] += vf[b];
    }
  }
  float* tp = tpartf + ((size_t)bh*16 + jc)*4096;
  #pragma unroll
  for (int a = 0; a < 4; ++a){
    float4 o; o.x = accT[a][0]; o.y = accT[a][1]; o.z = accT[a][2]; o.w = accT[a][3];
    *(float4*)&tp[(d1+a)*64 + d2] = o;
  }
  if (tid < 16){
    #pragma unroll
    for (int b = 0; b < 4; ++b) vsp[((size_t)bh*16 + jc)*64 + d2 + b] = accV[b];
  }
}

// reduce 16 f32 partials; store T transposed ([d2][d1]) as bf16 + vsum
__global__ void k_tred(const float* __restrict__ tpartf, const float* __restrict__ vsp,
                       unsigned short* __restrict__ TB, float* __restrict__ vsum){
  const int blk = blockIdx.x;            // 0..255
  const int bh = blk >> 4, part = blk & 15;
  const int tid = threadIdx.x;
  const int idx = part*256 + tid;
  const int dd1 = idx>>6, dd2 = idx&63;
  float s = 0.f;
  #pragma unroll
  for (int pr = 0; pr < 16; ++pr) s += tpartf[((size_t)bh*16 + pr)*4096 + idx];
  TB[(size_t)bh*4096 + dd2*64 + dd1] = f2b(s);
  if (part == 0 && tid < 64){
    float v = 0.f;
    #pragma unroll
    for (int pr = 0; pr < 16; ++pr) v += vsp[((size_t)bh*16 + pr)*64 + tid];
    vsum[bh*64 + tid] = v;
  }
}

// ---------------- LSE scan (coop-LDS, 3-deep prefetch, vmcnt(4), 25% VALU-exp) ----------
#define ASTAGE(U, BUFI) do { \
    const int ti_ = jbase + (((U)+phase)&15); \
    const size_t o_ = (size_t)ti_*64*DHEAD; \
    char* d_ = (char*)kt[BUFI]; \
    gld_lds16(kg0 + o_, d_ + s0*1024); \
    gld_lds16(kg1 + o_, d_ + s1*1024); } while(0)

#define ATILE(BUFI) do { \
    const char* buf_ = (const char*)kt[BUFI]; \
    _Pragma("unroll") \
    for (int kk = 0; kk < 4; ++kk){ \
      const int r_ = kk*16 + (lane&15); \
      const s16x8 b0_ = *(const s16x8*)(buf_ + r_*128 + ((((lane>>4))   ^ (r_&7))<<4)); \
      const s16x8 b1_ = *(const s16x8*)(buf_ + r_*128 + (((4+(lane>>4)) ^ (r_&7))<<4)); \
      f32x4 a0_ = {0.f,0.f,0.f,0.f}, a1_ = {0.f,0.f,0.f,0.f}; \
      f32x4 a2_ = {0.f,0.f,0.f,0.f}, a3_ = {0.f,0.f,0.f,0.f}; \
      __builtin_amdgcn_s_setprio(1); \
      a0_ = __builtin_amdgcn_mfma_f32_16x16x32_bf16(aq[0][0], b0_, a0_, 0,0,0); \
      a0_ = __builtin_amdgcn_mfma_f32_16x16x32_bf16(aq[0][1], b1_, a0_, 0,0,0); \
      a1_ = __builtin_amdgcn_mfma_f32_16x16x32_bf16(aq[1][0], b0_, a1_, 0,0,0); \
      a1_ = __builtin_amdgcn_mfma_f32_16x16x32_bf16(aq[1][1], b1_, a1_, 0,0,0); \
      a2_ = __builtin_amdgcn_mfma_f32_16x16x32_bf16(aq[2][0], b0_, a2_, 0,0,0); \
      a2_ = __builtin_amdgcn_mfma_f32_16x16x32_bf16(aq[2][1], b1_, a2_, 0,0,0); \
      a3_ = __builtin_amdgcn_mfma_f32_16x16x32_bf16(aq[3][0], b0_, a3_, 0,0,0); \
      a3_ = __builtin_amdgcn_mfma_f32_16x16x32_bf16(aq[3][1], b1_, a3_, 0,0,0); \
      __builtin_amdgcn_s_setprio(0); \
      _Pragma("unroll") \
      for (int rr = 0; rr < 4; ++rr){ \
        lsum[0][rr] += __builtin_amdgcn_exp2f(a0_[rr]); \
        lsum[1][rr] += __builtin_amdgcn_exp2f(a1_[rr]); \
        lsum[2][rr] += __builtin_amdgcn_exp2f(a2_[rr]); \
        lsum[3][rr] += fexp2(a3_[rr]); \
      } \
    } } while(0)

#define APHASE(U) do { \
    if ((U) <= 13)      { asm volatile("s_waitcnt vmcnt(4)" ::: "memory"); } \
    else if ((U) == 14) { asm volatile("s_waitcnt vmcnt(2)" ::: "memory"); } \
    else                { asm volatile("s_waitcnt vmcnt(0)" ::: "memory"); } \
    __builtin_amdgcn_s_barrier(); \
    asm volatile("" ::: "memory"); \
    if ((U) <= 12) ASTAGE((U)+3, ((U)+3)&3); \
    ATILE((U)&3); } while(0)

__global__ __launch_bounds__(256) void k_attn(
    const unsigned short* __restrict__ qbuf, const unsigned short* __restrict__ kbuf,
    float* __restrict__ ps){
  __shared__ __align__(16) unsigned short kt[4][64*64]; // 4 x 8KB
  const int bid = blockIdx.x;
  const int idx = bid >> 3;                  // 0..127
  const int bh  = ((bid & 7) << 1) + (idx >> 6);
  const int rest = idx & 63;
  const int qchunk = rest >> 2;              // 0..15 (256 q-rows each)
  const int js = rest & 3;                   // j quarter: 16 tiles
  const int tid = threadIdx.x, w = tid>>6, lane = tid&63;
  const int q0 = qchunk*256 + w*64;          // this wave's 64 q-rows
  const unsigned short* Q = qbuf + (size_t)bh*NSEQ*DHEAD;
  const unsigned short* K = kbuf + (size_t)bh*NSEQ*DHEAD;

  s16x8 aq[4][2];
  #pragma unroll
  for (int g = 0; g < 4; ++g){
    const int qrow = q0 + g*16 + (lane&15);
    aq[g][0] = *(const s16x8*)(Q + (size_t)qrow*DHEAD + ((lane>>4)<<3));
    aq[g][1] = *(const s16x8*)(Q + (size_t)qrow*DHEAD + 32 + ((lane>>4)<<3));
  }

  const int s0 = w*2, s1 = w*2 + 1;
  const int srow0 = s0*8 + (lane>>3), srow1 = s1*8 + (lane>>3);
  const int sch = ((lane&7) ^ (lane>>3));
  const unsigned short* kg0 = K + (size_t)srow0*DHEAD + sch*8;
  const unsigned short* kg1 = K + (size_t)srow1*DHEAD + sch*8;

  const int phase = (idx*5) & 15;
  const int jbase = js*16;

  ASTAGE(0, 0);
  ASTAGE(1, 1);
  ASTAGE(2, 2);

  float lsum[4][4] = {};
  APHASE(0);  APHASE(1);  APHASE(2);  APHASE(3);
  APHASE(4);  APHASE(5);  APHASE(6);  APHASE(7);
  APHASE(8);  APHASE(9);  APHASE(10); APHASE(11);
  APHASE(12); APHASE(13); APHASE(14); APHASE(15);

  #pragma unroll
  for (int m = 1; m < 16; m <<= 1)
    #pragma unroll
    for (int g = 0; g < 4; ++g)
      #pragma unroll
      for (int r = 0; r < 4; ++r) lsum[g][r] += __shfl_xor(lsum[g][r], m, 16);

  if ((lane&15) == 0){
    float* pp = ps + ((size_t)js*NBH + bh)*NSEQ;
    #pragma unroll
    for (int g = 0; g < 4; ++g)
      #pragma unroll
      for (int r = 0; r < 4; ++r)
        pp[q0 + g*16 + (lane>>4)*4 + r] = lsum[g][r];
  }
}

// ---------------- finish: lse + O = ln2*(Q'@T - lse2*Vsum) ----------------
__global__ __launch_bounds__(256) void k_attn_fin(
    const unsigned short* __restrict__ qbuf, const unsigned short* __restrict__ TB,
    const float* __restrict__ vsum, const float* __restrict__ ps,
    unsigned short* __restrict__ om){
  const int bid = blockIdx.x;                // 1024 = 16 bh x 64 qchunk
  const int bh = bid >> 6, qchunk = bid & 63;
  const int tid = threadIdx.x, w = tid>>6, lane = tid&63;
  const int q0 = qchunk*64 + w*16;
  const unsigned short* Q = qbuf + (size_t)bh*NSEQ*DHEAD;
  const int qrow = q0 + (lane&15);
  const s16x8 aq0 = *(const s16x8*)(Q + (size_t)qrow*DHEAD + ((lane>>4)<<3));
  const s16x8 aq1 = *(const s16x8*)(Q + (size_t)qrow*DHEAD + 32 + ((lane>>4)<<3));
  const float* p0 = ps + (size_t)bh*NSEQ;
  const float* p1 = ps + ((size_t)NBH   + bh)*NSEQ;
  const float* p2 = ps + ((size_t)2*NBH + bh)*NSEQ;
  const float* p3 = ps + ((size_t)3*NBH + bh)*NSEQ;
  float lse2[4];
  #pragma unroll
  for (int r = 0; r < 4; ++r){
    const int n = q0 + (lane>>4)*4 + r;
    lse2[r] = log2f((p0[n] + p1[n]) + (p2[n] + p3[n]));
  }
  const unsigned short* tb = TB + (size_t)bh*4096;
  const int b = bh>>3, h = bh&7;
  #pragma unroll
  for (int fc = 0; fc < 4; ++fc){
    const int d2 = fc*16 + (lane&15);
    const s16x8 t0 = *(const s16x8*)(tb + d2*64 + ((lane>>4)<<3));
    const s16x8 t1 = *(const s16x8*)(tb + d2*64 + 32 + ((lane>>4)<<3));
    const float vs = vsum[bh*64 + d2];
    f32x4 acc = {0.f,0.f,0.f,0.f};
    acc = __builtin_amdgcn_mfma_f32_16x16x32_bf16(aq0, t0, acc, 0,0,0);
    acc = __builtin_amdgcn_mfma_f32_16x16x32_bf16(aq1, t1, acc, 0,0,0);
    #pragma unroll
    for (int r = 0; r < 4; ++r){
      const int n = q0 + (lane>>4)*4 + r;
      const float val = 0.6931471805599453f * (acc[r] - lse2[r]*vs);
      om[((size_t)b*NSEQ + n)*DIM + h*DHEAD + d2] = f2b(val);
    }
  }
}

// ---------------- out GEMM: om[8192][512] @ w_out[512][512] + bias + residual ----------------
// XCD-swizzled 1D grid (256 = 8 xcd x 32).
#define OSTAGE(KS, B) do{ \
    const int k0_ = (KS)*32; \
    _Pragma("unroll") \
    for (int i_ = 0; i_ < 2; ++i_){ \
      const int slot_ = w*2 + i_; \
      const int r_ = slot_*16 + (lane>>2); \
      const int ch_ = (lane&3) ^ (r_&3); \
      gld_lds16(A  + (size_t)(m0+r_)*DIM + k0_ + ch_*8, (char*)at[B] + slot_*1024); \
      gld_lds16(Bt + (size_t)(n0+r_)*DIM + k0_ + ch_*8, (char*)bt[B] + slot_*1024); \
    }}while(0)

__global__ __launch_bounds__(256) void k_out_gemm(
    const unsigned short* __restrict__ A,   // om  [8192][512]
    const unsigned short* __restrict__ Bt,  // woT [512][512]
    const float* __restrict__ bias, const float* __restrict__ xres,
    float* __restrict__ out){
  __shared__ __align__(16) unsigned short at[2][128*32];
  __shared__ __align__(16) unsigned short bt[2][128*32];
  const int bid = blockIdx.x;
  const int swz = (bid & 7)*32 + (bid >> 3);   // bijective: 256 % 8 == 0
  const int n0 = (swz & 3)*128, m0 = (swz >> 2)*128;
  const int tid = threadIdx.x, w = tid>>6, lane = tid&63;
  const int wr = (w>>1)*64, wc = (w&1)*64;
  f32x4 acc[4][4] = {};
  OSTAGE(0, 0);
  for (int ks = 0; ks < 16; ++ks){
    __syncthreads();
    if (ks < 15) OSTAGE(ks+1, (ks+1)&1);
    const unsigned short* atc = at[ks&1];
    const unsigned short* btc = bt[ks&1];
    s16x8 af[4], bfr[4];
    #pragma unroll
    for (int f = 0; f < 4; ++f){
      const int rr = wr + f*16 + (lane&15);
      af[f]  = *(const s16x8*)((const char*)atc + rr*64 + ((((lane>>4)) ^ (rr&3))<<4));
      const int cc = wc + f*16 + (lane&15);
      bfr[f] = *(const s16x8*)((const char*)btc + cc*64 + ((((lane>>4)) ^ (cc&3))<<4));
    }
    #pragma unroll
    for (int fr = 0; fr < 4; ++fr)
      #pragma unroll
      for (int fc = 0; fc < 4; ++fc)
        acc[fr][fc] = __builtin_amdgcn_mfma_f32_16x16x32_bf16(bfr[fc], af[fr], acc[fr][fc], 0,0,0);
  }
  #pragma unroll
  for (int fr = 0; fr < 4; ++fr){
    const int row = m0 + wr + fr*16 + (lane&15);
    #pragma unroll
    for (int fc = 0; fc < 4; ++fc){
      const int col0 = n0 + wc + fc*16 + ((lane>>4)<<2);
      const float4 bb = *(const float4*)&bias[col0];
      const float4 xr = *(const float4*)&xres[(size_t)row*DIM + col0];
      float4 o;
      o.x = acc[fr][fc][0] + bb.x + xr.x;
      o.y = acc[fr][fc][1] + bb.y + xr.y;
      o.z = acc[fr][fc][2] + bb.z + xr.z;
      o.w = acc[fr][fc][3] + bb.w + xr.w;
      *(float4*)&out[(size_t)row*DIM + col0] = o;
    }
  }
}

extern "C" void kernel_launch(void* const* d_in, const int* in_sizes, int n_in,
                              void* d_out, int out_size, void* d_ws, size_t ws_size,
                              hipStream_t stream){
  const float* x    = (const float*)d_in[0];
  const float* wqkv = (const float*)d_in[1];
  const float* wout = (const float*)d_in[2];
  const float* bout = (const float*)d_in[3];
  float* out = (float*)d_out;

  char* p = (char*)d_ws;
  unsigned short* xb   = (unsigned short*)p; p += (size_t)MROWS*DIM*2;
  unsigned short* wqT  = (unsigned short*)p; p += (size_t)NQKV*DIM*2;
  unsigned short* woT  = (unsigned short*)p; p += (size_t)DIM*DIM*2;
  unsigned short* qbuf = (unsigned short*)p; p += (size_t)NBH*NSEQ*DHEAD*2;
  unsigned short* kbuf = (unsigned short*)p; p += (size_t)NBH*NSEQ*DHEAD*2;
  unsigned short* vbuf = (unsigned short*)p; p += (size_t)NBH*NSEQ*DHEAD*2;
  float* tpartf        = (float*)p;          p += (size_t)NBH*16*4096*4;
  float* vsp           = (float*)p;          p += (size_t)NBH*16*64*4;
  unsigned short* TB   = (unsigned short*)p; p += (size_t)NBH*64*64*2;
  float* vsum          = (float*)p;          p += (size_t)NBH*64*4;
  unsigned short* om   = (unsigned short*)p; p += (size_t)MROWS*DIM*2;
  float* ps            = (float*)p;          p += (size_t)4*NBH*NSEQ*4;

  k_prep<<<dim3(4096 + 768 + 256), dim3(256), 0, stream>>>(x, xb, wqkv, wqT, wout, woT);
  k_qkv_gemm<<<dim3(768), dim3(256), 0, stream>>>(xb, wqT, qbuf, kbuf, vbuf);
  k_tpart<<<dim3(16, NBH), dim3(256), 0, stream>>>(kbuf, vbuf, tpartf, vsp);
  k_tred<<<dim3(256), dim3(256), 0, stream>>>(tpartf, vsp, TB, vsum);
  k_attn<<<dim3(1024), dim3(256), 0, stream>>>(qbuf, kbuf, ps);
  k_attn_fin<<<dim3(1024), dim3(256), 0, stream>>>(qbuf, TB, vsum, ps, om);
  k_out_gemm<<<dim3(256), dim3(256), 0, stream>>>(om, woT, bout, x, out);
}

// Round 20
// 119.450 us; speedup vs baseline: 1.8164x; 1.0021x over previous
//
#include <hip/hip_runtime.h>
#include <stdint.h>

#define NSEQ   4096
#define BATCH  2
#define NHEAD  8
#define DHEAD  64
#define DIM    512
#define NQKV   1536
#define MROWS  (BATCH*NSEQ)   // 8192
#define NBH    (BATCH*NHEAD)  // 16

typedef float  f32x4 __attribute__((ext_vector_type(4)));
typedef short  s16x8 __attribute__((ext_vector_type(8)));

__device__ __forceinline__ unsigned short f2b(float f){
  unsigned int u = __float_as_uint(f);
  u += 0x7FFFu + ((u >> 16) & 1u);
  return (unsigned short)(u >> 16);
}
__device__ __forceinline__ float b2f(unsigned short h){
  return __uint_as_float(((unsigned int)h) << 16);
}
__device__ __forceinline__ void gld_lds16(const void* g, void* l){
  __builtin_amdgcn_global_load_lds((const __attribute__((address_space(1))) unsigned int*)g,
                                   (__attribute__((address_space(3))) unsigned int*)l, 16, 0, 0);
}
// Schraudolph fast exp2 on the VALU pipe (v_fma + v_cvt_i32). Rel err <= ~4%.
__device__ __forceinline__ float fexp2(float x){
  return __uint_as_float((unsigned)(int)__builtin_fmaf(x, 8388608.f, 1064866805.f));
}

// ---------------- fused prep: x->bf16, wqkv^T->bf16, wout^T->bf16 ----------------
__global__ void k_prep(const float* __restrict__ x, unsigned short* __restrict__ xb,
                       const float* __restrict__ wqkv, unsigned short* __restrict__ wqT,
                       const float* __restrict__ wout, unsigned short* __restrict__ woT){
  __shared__ float t[32][33];
  const int b = blockIdx.x;
  if (b < 4096){                       // cvt: 8192x512 via float4
    const int i = b*256 + threadIdx.x;
    float4 v = ((const float4*)x)[i];
    ushort4 o;
    o.x = f2b(v.x); o.y = f2b(v.y); o.z = f2b(v.z); o.w = f2b(v.w);
    ((ushort4*)xb)[i] = o;
  } else {
    const float* in; unsigned short* out; int R, C, cb, rb;
    if (b < 4096 + 768){               // wqkv [512][1536] -> [1536][512]
      const int q = b - 4096; in = wqkv; out = wqT; R = DIM; C = NQKV;
      cb = (q % 48)*32; rb = (q / 48)*32;
    } else {                           // wout [512][512] -> [512][512]
      const int q = b - 4096 - 768; in = wout; out = woT; R = DIM; C = DIM;
      cb = (q & 15)*32; rb = (q >> 4)*32;
    }
    const int tx = threadIdx.x & 31, ty = threadIdx.x >> 5;
    #pragma unroll
    for (int s = 0; s < 32; s += 8) t[ty+s][tx] = in[(size_t)(rb+ty+s)*C + cb + tx];
    __syncthreads();
    #pragma unroll
    for (int s = 0; s < 32; s += 8) out[(size_t)(cb+ty+s)*R + rb + tx] = f2b(t[tx][ty+s]);
  }
}

// ---------------- QKV GEMM: [8192][512] @ [512][1536] (B given transposed) ----------------
// XCD-swizzled 1D grid (768 = 8 xcd x 96).
#define QSTAGE(KS, B) do{ \
    const int k0_ = (KS)*32; \
    _Pragma("unroll") \
    for (int i_ = 0; i_ < 2; ++i_){ \
      const int slot_ = w*2 + i_; \
      const int r_ = slot_*16 + (lane>>2); \
      const int ch_ = (lane&3) ^ (r_&3); \
      gld_lds16(A  + (size_t)(m0+r_)*DIM + k0_ + ch_*8, (char*)at[B] + slot_*1024); \
      gld_lds16(Bt + (size_t)(n0+r_)*DIM + k0_ + ch_*8, (char*)bt[B] + slot_*1024); \
    }}while(0)

__global__ __launch_bounds__(256) void k_qkv_gemm(
    const unsigned short* __restrict__ A,   // xb  [8192][512]
    const unsigned short* __restrict__ Bt,  // wqT [1536][512]
    unsigned short* __restrict__ qbuf, unsigned short* __restrict__ kbuf,
    unsigned short* __restrict__ vbuf){
  __shared__ __align__(16) unsigned short at[2][128*32];
  __shared__ __align__(16) unsigned short bt[2][128*32];
  const int bid = blockIdx.x;
  const int swz = (bid & 7)*96 + (bid >> 3);   // bijective: 768 % 8 == 0
  const int n0 = (swz % 12)*128, m0 = (swz / 12)*128;
  const int tid = threadIdx.x, w = tid>>6, lane = tid&63;
  const int wr = (w>>1)*64, wc = (w&1)*64;
  f32x4 acc[4][4] = {};
  QSTAGE(0, 0);
  for (int ks = 0; ks < 16; ++ks){
    __syncthreads();
    if (ks < 15) QSTAGE(ks+1, (ks+1)&1);
    const unsigned short* atc = at[ks&1];
    const unsigned short* btc = bt[ks&1];
    s16x8 af[4], bfr[4];
    #pragma unroll
    for (int f = 0; f < 4; ++f){
      const int rr = wr + f*16 + (lane&15);
      af[f]  = *(const s16x8*)((const char*)atc + rr*64 + ((((lane>>4)) ^ (rr&3))<<4));
      const int cc = wc + f*16 + (lane&15);
      bfr[f] = *(const s16x8*)((const char*)btc + cc*64 + ((((lane>>4)) ^ (cc&3))<<4));
    }
    #pragma unroll
    for (int fr = 0; fr < 4; ++fr)
      #pragma unroll
      for (int fc = 0; fc < 4; ++fc)
        acc[fr][fc] = __builtin_amdgcn_mfma_f32_16x16x32_bf16(bfr[fc], af[fr], acc[fr][fc], 0,0,0);
  }
  const float QS = 0.18033688011112042f;
  #pragma unroll
  for (int fr = 0; fr < 4; ++fr){
    const int row = m0 + wr + fr*16 + (lane&15);
    const int b = row >> 12, n = row & 4095;
    #pragma unroll
    for (int fc = 0; fc < 4; ++fc){
      const int col0 = n0 + wc + fc*16 + ((lane>>4)<<2);
      const int which = col0 >> 9;
      const int h = (col0 & 511) >> 6;
      const int d = col0 & 63;
      unsigned short* dst = (which==0) ? qbuf : ((which==1) ? kbuf : vbuf);
      const float sc = (which==0) ? QS : 1.f;
      ushort4 o;
      o.x = f2b(acc[fr][fc][0]*sc);
      o.y = f2b(acc[fr][fc][1]*sc);
      o.z = f2b(acc[fr][fc][2]*sc);
      o.w = f2b(acc[fr][fc][3]*sc);
      *(ushort4*)(dst + (size_t)((b*NHEAD + h)*NSEQ + n)*DHEAD + d) = o;
    }
  }
}

// ---------------- T = K^T V partials: 1D grid, bh pinned to XCD (matches attn) ----------
// 256 blocks = 8 xcd x 2 bh x 16 jc; xcd g owns bh {2g,2g+1} exactly like k_attn,
// so its K/V stream stays in the L2 that attn later reads K from.
__global__ __launch_bounds__(256) void k_tpart(
    const unsigned short* __restrict__ kbuf, const unsigned short* __restrict__ vbuf,
    float* __restrict__ tpartf, float* __restrict__ vsp){
  __shared__ __align__(16) unsigned short kt[64*64];
  __shared__ __align__(16) unsigned short vt[64*64];
  const int bid = blockIdx.x;
  const int idx = bid >> 3;                   // 0..31
  const int bh  = ((bid & 7) << 1) + (idx >> 4);
  const int jc  = idx & 15;                   // 0..15
  const unsigned short* K = kbuf + (size_t)bh*NSEQ*DHEAD;
  const unsigned short* V = vbuf + (size_t)bh*NSEQ*DHEAD;
  const int tid = threadIdx.x;
  const int d1 = (tid>>4)<<2, d2 = (tid&15)<<2;
  float accT[4][4] = {{0.f}};
  float accV[4] = {0.f,0.f,0.f,0.f};
  for (int st = 0; st < 4; ++st){
    const int j0 = jc*256 + st*64;
    __syncthreads();
    #pragma unroll
    for (int c = 0; c < 2; ++c){
      const int q = tid + 256*c;
      const int row = q>>3, ch = q&7;
      *(float4*)((char*)kt + row*128 + ch*16) = *(const float4*)((const char*)K + (size_t)(j0+row)*128 + ch*16);
      *(float4*)((char*)vt + row*128 + ch*16) = *(const float4*)((const char*)V + (size_t)(j0+row)*128 + ch*16);
    }
    __syncthreads();
    for (int jj = 0; jj < 64; ++jj){
      const ushort4 k4 = *(const ushort4*)(kt + jj*64 + d1);
      const ushort4 v4 = *(const ushort4*)(vt + jj*64 + d2);
      float kf[4] = {b2f(k4.x), b2f(k4.y), b2f(k4.z), b2f(k4.w)};
      float vf[4] = {b2f(v4.x), b2f(v4.y), b2f(v4.z), b2f(v4.w)};
      #pragma unroll
      for (int a = 0; a < 4; ++a)
        #pragma unroll
        for (int b = 0; b < 4; ++b) accT[a][b] += kf[a]*vf[b];
      #pragma unroll
      for (int b = 0; b < 4; ++b) accV[b] += vf[b];
    }
  }
  float* tp = tpartf + ((size_t)bh*16 + jc)*4096;
  #pragma unroll
  for (int a = 0; a < 4; ++a){
    float4 o; o.x = accT[a][0]; o.y = accT[a][1]; o.z = accT[a][2]; o.w = accT[a][3];
    *(float4*)&tp[(d1+a)*64 + d2] = o;
  }
  if (tid < 16){
    #pragma unroll
    for (int b = 0; b < 4; ++b) vsp[((size_t)bh*16 + jc)*64 + d2 + b] = accV[b];
  }
}

// reduce 16 f32 partials; store T transposed ([d2][d1]) as bf16 + vsum
__global__ void k_tred(const float* __restrict__ tpartf, const float* __restrict__ vsp,
                       unsigned short* __restrict__ TB, float* __restrict__ vsum){
  const int blk = blockIdx.x;            // 0..255
  const int bh = blk >> 4, part = blk & 15;
  const int tid = threadIdx.x;
  const int idx = part*256 + tid;
  const int dd1 = idx>>6, dd2 = idx&63;
  float s = 0.f;
  #pragma unroll
  for (int pr = 0; pr < 16; ++pr) s += tpartf[((size_t)bh*16 + pr)*4096 + idx];
  TB[(size_t)bh*4096 + dd2*64 + dd1] = f2b(s);
  if (part == 0 && tid < 64){
    float v = 0.f;
    #pragma unroll
    for (int pr = 0; pr < 16; ++pr) v += vsp[((size_t)bh*16 + pr)*64 + tid];
    vsum[bh*64 + tid] = v;
  }
}

// ---------------- LSE scan (coop-LDS, 3-deep prefetch, vmcnt(4), 25% VALU-exp) ----------
#define ASTAGE(U, BUFI) do { \
    const int ti_ = jbase + (((U)+phase)&15); \
    const size_t o_ = (size_t)ti_*64*DHEAD; \
    char* d_ = (char*)kt[BUFI]; \
    gld_lds16(kg0 + o_, d_ + s0*1024); \
    gld_lds16(kg1 + o_, d_ + s1*1024); } while(0)

#define ATILE(BUFI) do { \
    const char* buf_ = (const char*)kt[BUFI]; \
    _Pragma("unroll") \
    for (int kk = 0; kk < 4; ++kk){ \
      const int r_ = kk*16 + (lane&15); \
      const s16x8 b0_ = *(const s16x8*)(buf_ + r_*128 + ((((lane>>4))   ^ (r_&7))<<4)); \
      const s16x8 b1_ = *(const s16x8*)(buf_ + r_*128 + (((4+(lane>>4)) ^ (r_&7))<<4)); \
      f32x4 a0_ = {0.f,0.f,0.f,0.f}, a1_ = {0.f,0.f,0.f,0.f}; \
      f32x4 a2_ = {0.f,0.f,0.f,0.f}, a3_ = {0.f,0.f,0.f,0.f}; \
      __builtin_amdgcn_s_setprio(1); \
      a0_ = __builtin_amdgcn_mfma_f32_16x16x32_bf16(aq[0][0], b0_, a0_, 0,0,0); \
      a0_ = __builtin_amdgcn_mfma_f32_16x16x32_bf16(aq[0][1], b1_, a0_, 0,0,0); \
      a1_ = __builtin_amdgcn_mfma_f32_16x16x32_bf16(aq[1][0], b0_, a1_, 0,0,0); \
      a1_ = __builtin_amdgcn_mfma_f32_16x16x32_bf16(aq[1][1], b1_, a1_, 0,0,0); \
      a2_ = __builtin_amdgcn_mfma_f32_16x16x32_bf16(aq[2][0], b0_, a2_, 0,0,0); \
      a2_ = __builtin_amdgcn_mfma_f32_16x16x32_bf16(aq[2][1], b1_, a2_, 0,0,0); \
      a3_ = __builtin_amdgcn_mfma_f32_16x16x32_bf16(aq[3][0], b0_, a3_, 0,0,0); \
      a3_ = __builtin_amdgcn_mfma_f32_16x16x32_bf16(aq[3][1], b1_, a3_, 0,0,0); \
      __builtin_amdgcn_s_setprio(0); \
      _Pragma("unroll") \
      for (int rr = 0; rr < 4; ++rr){ \
        lsum[0][rr] += __builtin_amdgcn_exp2f(a0_[rr]); \
        lsum[1][rr] += __builtin_amdgcn_exp2f(a1_[rr]); \
        lsum[2][rr] += __builtin_amdgcn_exp2f(a2_[rr]); \
        lsum[3][rr] += fexp2(a3_[rr]); \
      } \
    } } while(0)

#define APHASE(U) do { \
    if ((U) <= 13)      { asm volatile("s_waitcnt vmcnt(4)" ::: "memory"); } \
    else if ((U) == 14) { asm volatile("s_waitcnt vmcnt(2)" ::: "memory"); } \
    else                { asm volatile("s_waitcnt vmcnt(0)" ::: "memory"); } \
    __builtin_amdgcn_s_barrier(); \
    asm volatile("" ::: "memory"); \
    if ((U) <= 12) ASTAGE((U)+3, ((U)+3)&3); \
    ATILE((U)&3); } while(0)

__global__ __launch_bounds__(256) void k_attn(
    const unsigned short* __restrict__ qbuf, const unsigned short* __restrict__ kbuf,
    float* __restrict__ ps){
  __shared__ __align__(16) unsigned short kt[4][64*64]; // 4 x 8KB
  const int bid = blockIdx.x;
  const int idx = bid >> 3;                  // 0..127
  const int bh  = ((bid & 7) << 1) + (idx >> 6);
  const int rest = idx & 63;
  const int qchunk = rest >> 2;              // 0..15 (256 q-rows each)
  const int js = rest & 3;                   // j quarter: 16 tiles
  const int tid = threadIdx.x, w = tid>>6, lane = tid&63;
  const int q0 = qchunk*256 + w*64;          // this wave's 64 q-rows
  const unsigned short* Q = qbuf + (size_t)bh*NSEQ*DHEAD;
  const unsigned short* K = kbuf + (size_t)bh*NSEQ*DHEAD;

  s16x8 aq[4][2];
  #pragma unroll
  for (int g = 0; g < 4; ++g){
    const int qrow = q0 + g*16 + (lane&15);
    aq[g][0] = *(const s16x8*)(Q + (size_t)qrow*DHEAD + ((lane>>4)<<3));
    aq[g][1] = *(const s16x8*)(Q + (size_t)qrow*DHEAD + 32 + ((lane>>4)<<3));
  }

  const int s0 = w*2, s1 = w*2 + 1;
  const int srow0 = s0*8 + (lane>>3), srow1 = s1*8 + (lane>>3);
  const int sch = ((lane&7) ^ (lane>>3));
  const unsigned short* kg0 = K + (size_t)srow0*DHEAD + sch*8;
  const unsigned short* kg1 = K + (size_t)srow1*DHEAD + sch*8;

  const int phase = (idx*5) & 15;
  const int jbase = js*16;

  ASTAGE(0, 0);
  ASTAGE(1, 1);
  ASTAGE(2, 2);

  float lsum[4][4] = {};
  APHASE(0);  APHASE(1);  APHASE(2);  APHASE(3);
  APHASE(4);  APHASE(5);  APHASE(6);  APHASE(7);
  APHASE(8);  APHASE(9);  APHASE(10); APHASE(11);
  APHASE(12); APHASE(13); APHASE(14); APHASE(15);

  #pragma unroll
  for (int m = 1; m < 16; m <<= 1)
    #pragma unroll
    for (int g = 0; g < 4; ++g)
      #pragma unroll
      for (int r = 0; r < 4; ++r) lsum[g][r] += __shfl_xor(lsum[g][r], m, 16);

  if ((lane&15) == 0){
    float* pp = ps + ((size_t)js*NBH + bh)*NSEQ;
    #pragma unroll
    for (int g = 0; g < 4; ++g)
      #pragma unroll
      for (int r = 0; r < 4; ++r)
        pp[q0 + g*16 + (lane>>4)*4 + r] = lsum[g][r];
  }
}

// ---------------- finish: lse + O = ln2*(Q'@T - lse2*Vsum) ----------------
// Same bh->XCD pinning as k_attn: the XCD that scanned bh has its qbuf panels
// L2-warm; 1024 blocks = 8 xcd x 2 bh x 64 qchunk.
__global__ __launch_bounds__(256) void k_attn_fin(
    const unsigned short* __restrict__ qbuf, const unsigned short* __restrict__ TB,
    const float* __restrict__ vsum, const float* __restrict__ ps,
    unsigned short* __restrict__ om){
  const int bid = blockIdx.x;
  const int idx = bid >> 3;                  // 0..127
  const int bh  = ((bid & 7) << 1) + (idx >> 6);
  const int qchunk = idx & 63;
  const int tid = threadIdx.x, w = tid>>6, lane = tid&63;
  const int q0 = qchunk*64 + w*16;
  const unsigned short* Q = qbuf + (size_t)bh*NSEQ*DHEAD;
  const int qrow = q0 + (lane&15);
  const s16x8 aq0 = *(const s16x8*)(Q + (size_t)qrow*DHEAD + ((lane>>4)<<3));
  const s16x8 aq1 = *(const s16x8*)(Q + (size_t)qrow*DHEAD + 32 + ((lane>>4)<<3));
  const float* p0 = ps + (size_t)bh*NSEQ;
  const float* p1 = ps + ((size_t)NBH   + bh)*NSEQ;
  const float* p2 = ps + ((size_t)2*NBH + bh)*NSEQ;
  const float* p3 = ps + ((size_t)3*NBH + bh)*NSEQ;
  float lse2[4];
  #pragma unroll
  for (int r = 0; r < 4; ++r){
    const int n = q0 + (lane>>4)*4 + r;
    lse2[r] = log2f((p0[n] + p1[n]) + (p2[n] + p3[n]));
  }
  const unsigned short* tb = TB + (size_t)bh*4096;
  const int b = bh>>3, h = bh&7;
  #pragma unroll
  for (int fc = 0; fc < 4; ++fc){
    const int d2 = fc*16 + (lane&15);
    const s16x8 t0 = *(const s16x8*)(tb + d2*64 + ((lane>>4)<<3));
    const s16x8 t1 = *(const s16x8*)(tb + d2*64 + 32 + ((lane>>4)<<3));
    const float vs = vsum[bh*64 + d2];
    f32x4 acc = {0.f,0.f,0.f,0.f};
    acc = __builtin_amdgcn_mfma_f32_16x16x32_bf16(aq0, t0, acc, 0,0,0);
    acc = __builtin_amdgcn_mfma_f32_16x16x32_bf16(aq1, t1, acc, 0,0,0);
    #pragma unroll
    for (int r = 0; r < 4; ++r){
      const int n = q0 + (lane>>4)*4 + r;
      const float val = 0.6931471805599453f * (acc[r] - lse2[r]*vs);
      om[((size_t)b*NSEQ + n)*DIM + h*DHEAD + d2] = f2b(val);
    }
  }
}

// ---------------- out GEMM: om[8192][512] @ w_out[512][512] + bias + residual ----------------
// XCD-swizzled 1D grid (256 = 8 xcd x 32).
#define OSTAGE(KS, B) do{ \
    const int k0_ = (KS)*32; \
    _Pragma("unroll") \
    for (int i_ = 0; i_ < 2; ++i_){ \
      const int slot_ = w*2 + i_; \
      const int r_ = slot_*16 + (lane>>2); \
      const int ch_ = (lane&3) ^ (r_&3); \
      gld_lds16(A  + (size_t)(m0+r_)*DIM + k0_ + ch_*8, (char*)at[B] + slot_*1024); \
      gld_lds16(Bt + (size_t)(n0+r_)*DIM + k0_ + ch_*8, (char*)bt[B] + slot_*1024); \
    }}while(0)

__global__ __launch_bounds__(256) void k_out_gemm(
    const unsigned short* __restrict__ A,   // om  [8192][512]
    const unsigned short* __restrict__ Bt,  // woT [512][512]
    const float* __restrict__ bias, const float* __restrict__ xres,
    float* __restrict__ out){
  __shared__ __align__(16) unsigned short at[2][128*32];
  __shared__ __align__(16) unsigned short bt[2][128*32];
  const int bid = blockIdx.x;
  const int swz = (bid & 7)*32 + (bid >> 3);   // bijective: 256 % 8 == 0
  const int n0 = (swz & 3)*128, m0 = (swz >> 2)*128;
  const int tid = threadIdx.x, w = tid>>6, lane = tid&63;
  const int wr = (w>>1)*64, wc = (w&1)*64;
  f32x4 acc[4][4] = {};
  OSTAGE(0, 0);
  for (int ks = 0; ks < 16; ++ks){
    __syncthreads();
    if (ks < 15) OSTAGE(ks+1, (ks+1)&1);
    const unsigned short* atc = at[ks&1];
    const unsigned short* btc = bt[ks&1];
    s16x8 af[4], bfr[4];
    #pragma unroll
    for (int f = 0; f < 4; ++f){
      const int rr = wr + f*16 + (lane&15);
      af[f]  = *(const s16x8*)((const char*)atc + rr*64 + ((((lane>>4)) ^ (rr&3))<<4));
      const int cc = wc + f*16 + (lane&15);
      bfr[f] = *(const s16x8*)((const char*)btc + cc*64 + ((((lane>>4)) ^ (cc&3))<<4));
    }
    #pragma unroll
    for (int fr = 0; fr < 4; ++fr)
      #pragma unroll
      for (int fc = 0; fc < 4; ++fc)
        acc[fr][fc] = __builtin_amdgcn_mfma_f32_16x16x32_bf16(bfr[fc], af[fr], acc[fr][fc], 0,0,0);
  }
  #pragma unroll
  for (int fr = 0; fr < 4; ++fr){
    const int row = m0 + wr + fr*16 + (lane&15);
    #pragma unroll
    for (int fc = 0; fc < 4; ++fc){
      const int col0 = n0 + wc + fc*16 + ((lane>>4)<<2);
      const float4 bb = *(const float4*)&bias[col0];
      const float4 xr = *(const float4*)&xres[(size_t)row*DIM + col0];
      float4 o;
      o.x = acc[fr][fc][0] + bb.x + xr.x;
      o.y = acc[fr][fc][1] + bb.y + xr.y;
      o.z = acc[fr][fc][2] + bb.z + xr.z;
      o.w = acc[fr][fc][3] + bb.w + xr.w;
      *(float4*)&out[(size_t)row*DIM + col0] = o;
    }
  }
}

extern "C" void kernel_launch(void* const* d_in, const int* in_sizes, int n_in,
                              void* d_out, int out_size, void* d_ws, size_t ws_size,
                              hipStream_t stream){
  const float* x    = (const float*)d_in[0];
  const float* wqkv = (const float*)d_in[1];
  const float* wout = (const float*)d_in[2];
  const float* bout = (const float*)d_in[3];
  float* out = (float*)d_out;

  char* p = (char*)d_ws;
  unsigned short* xb   = (unsigned short*)p; p += (size_t)MROWS*DIM*2;
  unsigned short* wqT  = (unsigned short*)p; p += (size_t)NQKV*DIM*2;
  unsigned short* woT  = (unsigned short*)p; p += (size_t)DIM*DIM*2;
  unsigned short* qbuf = (unsigned short*)p; p += (size_t)NBH*NSEQ*DHEAD*2;
  unsigned short* kbuf = (unsigned short*)p; p += (size_t)NBH*NSEQ*DHEAD*2;
  unsigned short* vbuf = (unsigned short*)p; p += (size_t)NBH*NSEQ*DHEAD*2;
  float* tpartf        = (float*)p;          p += (size_t)NBH*16*4096*4;
  float* vsp           = (float*)p;          p += (size_t)NBH*16*64*4;
  unsigned short* TB   = (unsigned short*)p; p += (size_t)NBH*64*64*2;
  float* vsum          = (float*)p;          p += (size_t)NBH*64*4;
  unsigned short* om   = (unsigned short*)p; p += (size_t)MROWS*DIM*2;
  float* ps            = (float*)p;          p += (size_t)4*NBH*NSEQ*4;

  k_prep<<<dim3(4096 + 768 + 256), dim3(256), 0, stream>>>(x, xb, wqkv, wqT, wout, woT);
  k_qkv_gemm<<<dim3(768), dim3(256), 0, stream>>>(xb, wqT, qbuf, kbuf, vbuf);
  k_tpart<<<dim3(256), dim3(256), 0, stream>>>(kbuf, vbuf, tpartf, vsp);
  k_tred<<<dim3(256), dim3(256), 0, stream>>>(tpartf, vsp, TB, vsum);
  k_attn<<<dim3(1024), dim3(256), 0, stream>>>(qbuf, kbuf, ps);
  k_attn_fin<<<dim3(1024), dim3(256), 0, stream>>>(qbuf, TB, vsum, ps, om);
  k_out_gemm<<<dim3(256), dim3(256), 0, stream>>>(om, woT, bout, x, out);
}